// Round 25
// baseline (140.504 us; speedup 1.0000x reference)
//
#include <hip/hip_runtime.h>
#include <hip/hip_bf16.h>

#define N_NODES 50000
#define P_PATHS 200000
#define N_ROWS  250000
#define L_EDGES 6
#define T_LEN   128
#define F_BINS  65
#define EPSF    1e-12f
#define PIF     3.14159265358979323846f
#define COORD_ELEMS ((size_t)2 * (P_PATHS + N_NODES))   // 500000 f32
#define FREQ_BYTES  ((size_t)N_NODES * F_BINS * 8)      // 26 MB mark
#define ATILE_OFF   ((size_t)32 * 1024 * 1024)
#define XTAB_OFF    ((size_t)96 * 1024 * 1024)
#define PCON_OFF    ((size_t)112 * 1024 * 1024)
#define KDIM  128
#define KPADN 128
#define ROWS_BLK 64
#define PATH_TILES (P_PATHS / ROWS_BLK)                 // 3125 (exact)
#define TILES ((N_ROWS + ROWS_BLK - 1) / ROWS_BLK)      // 3907
#define GEMM_GRID 1024
#define STILES ((N_NODES + ROWS_BLK - 1) / ROWS_BLK)    // 782
#define DPAD 132                                        // LDS D-tile stride (floats)

typedef _Float16 v2h __attribute__((ext_vector_type(2)));
typedef _Float16 v4h __attribute__((ext_vector_type(4)));
typedef _Float16 v8h __attribute__((ext_vector_type(8)));
typedef float    v4f __attribute__((ext_vector_type(4)));

__device__ __forceinline__ float softplus_(float x) {
    const float e = __expf(-fabsf(x));
    return fmaxf(x, 0.0f) + __logf(1.0f + e);
}

__device__ __forceinline__ float lgamma_pos_(float x) {
    const float ser = 1.000000000190015f
                    + 76.18009172947146f     / (x + 1.0f)
                    - 86.50532032941677f     / (x + 2.0f)
                    + 24.01409824083091f     / (x + 3.0f)
                    - 1.231739572450155f     / (x + 4.0f)
                    + 0.1208650973866179e-2f / (x + 5.0f)
                    - 0.5395239384953e-5f    / (x + 6.0f);
    const float tmp = x + 5.5f;
    return (x + 0.5f) * __logf(tmp) - tmp + __logf(2.5066282746310005f * ser / x);
}

// ---------------- K0: merged setup — Wt, W2t, pcons (unchanged) ----------------
__global__ __launch_bounds__(256) void irfa49x_setup(const float* __restrict__ params,
                                                     _Float16* __restrict__ Wt,
                                                     _Float16* __restrict__ W2t,
                                                     float4* __restrict__ pcons) {
    const int b = blockIdx.x;
    if (b < 64) {
        const int idx = b * 256 + threadIdx.x;
        const int t  = idx >> 7;
        const int kk = idx & 127;
        int j; float cj; bool is_sin;
        if (kk == 1) { j = 64; cj = 1.0f; is_sin = false; }
        else {
            j = kk >> 1;
            cj = (j == 0) ? 1.0f : 2.0f;
            is_sin = (kk & 1);
        }
        const int m = (j * t) & 127;
        const float th = (float)m * (PIF / 64.0f);
        const float tri = is_sin ? -__sinf(th) : __cosf(th);
        Wt[idx] = (_Float16)(cj * tri * (1.0f / 128.0f));
    } else if (b < 128) {
        const int idx = (b - 64) * 256 + threadIdx.x;
        const int kk = idx >> 7;
        const int t  = idx & 127;
        int j; bool is_sin;
        if (kk == 1) { j = 64; is_sin = false; }
        else { j = kk >> 1; is_sin = (kk & 1); }
        const int m = (j * t) & 127;
        const float th = (float)m * (PIF / 64.0f);
        W2t[idx] = (_Float16)(is_sin ? -__sinf(th) : __cosf(th));
    } else {
        const int n = (b - 128) * 256 + threadIdx.x;
        if (n >= N_NODES) return;
        const float a  = softplus_(params[2 * n + 0]) + 1.0f;
        const float bb = softplus_(params[2 * n + 1]) + 0.5f;
        const float lg = lgamma_pos_(a);
        const float lb = __logf(bb);
        float4 pc;
        pc.x = a - 1.0f;
        pc.y = 1.0f / bb;
        pc.z = -lg - a * lb;
        pc.w = 0.0f;
        pcons[n] = pc;
    }
}

// ---------------- K1a: gamma IRF samples -> fp16 xtab (unchanged) ----------------
__global__ __launch_bounds__(256) void irfa49w_xgen(const float4* __restrict__ pcons,
                                                    _Float16* __restrict__ xtab) {
    const int tid  = threadIdx.x;
    const int node = blockIdx.x * 2 + (tid >> 7);
    const int t    = tid & 127;
    const float4 pc = pcons[node];
    const float tc = (float)t + 0.5f;
    const float x  = __expf(fmaf(pc.x, __logf(tc), fmaf(-tc, pc.y, pc.z)));
    xtab[(size_t)node * T_LEN + t] = (_Float16)x;
}

// ---------------- K1b: spectrum GEMM (unchanged) ----------------
__global__ __launch_bounds__(256, 2) void irfa49x_spec(const _Float16* __restrict__ xtab,
                                                       const _Float16* __restrict__ W2t,
                                                       _Float16* __restrict__ freqh) {
    const int tid  = threadIdx.x;
    const int wv   = tid >> 6;
    const int lane = tid & 63;
    const int tcol = lane & 15;
    const int kg   = lane >> 4;
    const int rgrp = kg * 4;
    const int tile = blockIdx.x;

    v8h bf[4][8];
    #pragma unroll
    for (int kt = 0; kt < 4; ++kt) {
        #pragma unroll
        for (int nt = 0; nt < 8; ++nt) {
            bf[kt][nt] = *(const v8h*)&W2t[(nt * 16 + tcol) * 128 + kt * 32 + kg * 8];
        }
    }

    const int rowa = tile * ROWS_BLK + wv * 16 + tcol;
    v8h af[4];
    #pragma unroll
    for (int kt = 0; kt < 4; ++kt) {
        v8h v = (v8h){(_Float16)0.0f, (_Float16)0.0f, (_Float16)0.0f, (_Float16)0.0f,
                      (_Float16)0.0f, (_Float16)0.0f, (_Float16)0.0f, (_Float16)0.0f};
        if (rowa < N_NODES) v = *(const v8h*)&xtab[(size_t)rowa * T_LEN + kt * 32 + kg * 8];
        af[kt] = v;
    }

    v4f acc[8];
    #pragma unroll
    for (int nt = 0; nt < 8; ++nt) acc[nt] = (v4f){0.0f, 0.0f, 0.0f, 0.0f};
    #pragma unroll
    for (int kt = 0; kt < 4; ++kt) {
        #pragma unroll
        for (int nt = 0; nt < 8; ++nt) {
            acc[nt] = __builtin_amdgcn_mfma_f32_16x16x32_f16(af[kt], bf[kt][nt], acc[nt], 0, 0, 0);
        }
    }

    #pragma unroll
    for (int reg = 0; reg < 4; ++reg) {
        const int row = tile * ROWS_BLK + wv * 16 + rgrp + reg;
        if (row < N_NODES) {
            _Float16* op = freqh + (size_t)row * KPADN;
            #pragma unroll
            for (int nt = 0; nt < 8; ++nt) {
                op[nt * 16 + tcol] = (_Float16)acc[nt][reg];
            }
        }
    }
}

// ---------------- K2a: spectral product, adjacent-bin lanes, one 8B load/edge ----------------
__global__ __launch_bounds__(256) void irfa49y_prod(const _Float16* __restrict__ freqh,
                                                    const int* __restrict__ edges,
                                                    _Float16* __restrict__ Atile) {
    const int gt  = blockIdx.x * 256 + threadIdx.x;   // grid exact: 200000*32/256
    const int row = gt >> 5;
    const int tl  = gt & 31;        // lane owns bins 2tl, 2tl+1 (halves 4tl..4tl+3)
    _Float16* op = Atile + (size_t)row * KDIM;

    const int eb = row * L_EDGES;
    v4h fv[L_EDGES];
    #pragma unroll
    for (int j = 0; j < L_EDGES; ++j) {
        fv[j] = *(const v4h*)(freqh + (size_t)edges[eb + j] * KPADN + 4 * tl);
    }
    float p0r = 1.0f, p0i = 0.0f, p1r = 1.0f, p1i = 0.0f, q = 1.0f;
    #pragma unroll
    for (int j = 0; j < L_EDGES; ++j) {
        const float ax  = (float)fv[j][0];
        const float ayr = (float)fv[j][1];
        const float ay  = (tl == 0) ? 0.0f : ayr;     // lane0: bin0.im slot = f64.re
        float t1 = p0r * ax - p0i * ay;
        p0i      = p0r * ay + p0i * ax;
        p0r = t1;
        q *= ayr;                                     // meaningful on lane 0 only
        const float bx = (float)fv[j][2], by = (float)fv[j][3];
        float t2 = p1r * bx - p1i * by;
        p1i      = p1r * by + p1i * bx;
        p1r = t2;
    }
    v4h h;
    h[0] = (_Float16)p0r;
    h[1] = (tl == 0) ? (_Float16)q : (_Float16)p0i;
    h[2] = (_Float16)p1r;
    h[3] = (_Float16)p1i;
    *(v4h*)(op + 4 * tl) = h;
}

// ---------------- K2b: persistent MFMA GEMM + LDS-staged float4 flipped stores ----------------
__global__ __launch_bounds__(256, 2) void irfa49y_gemm(const _Float16* __restrict__ Atile,
                                                       const _Float16* __restrict__ freqh,
                                                       const _Float16* __restrict__ Wt,
                                                       float* __restrict__ out_agg) {
    __shared__ float sD[ROWS_BLK][DPAD];   // 33.8 KB; stride 132 breaks bank aliasing
    const int tid  = threadIdx.x;
    const int wv   = tid >> 6;
    const int lane = tid & 63;
    const int tcol = lane & 15;
    const int kg   = lane >> 4;
    const int rgrp = kg * 4;

    v8h bf[4][8];
    #pragma unroll
    for (int kt = 0; kt < 4; ++kt) {
        #pragma unroll
        for (int nt = 0; nt < 8; ++nt) {
            bf[kt][nt] = *(const v8h*)&Wt[(nt * 16 + tcol) * KDIM + kt * 32 + kg * 8];
        }
    }

    const int srow = tid >> 2;             // store phase: row 0..63
    const int scb0 = (tid & 3) * 8;        // 8 col-blocks of 4

    for (int tile = blockIdx.x; tile < TILES; tile += GEMM_GRID) {
        const int rowa = tile * ROWS_BLK + wv * 16 + tcol;
        const _Float16* ap = (tile < PATH_TILES)
            ? Atile + (size_t)rowa * KDIM + kg * 8
            : freqh + (size_t)(rowa - P_PATHS) * KPADN + kg * 8;

        v8h af[4];
        #pragma unroll
        for (int kt = 0; kt < 4; ++kt) {
            v8h v = (v8h){(_Float16)0.0f, (_Float16)0.0f, (_Float16)0.0f, (_Float16)0.0f,
                          (_Float16)0.0f, (_Float16)0.0f, (_Float16)0.0f, (_Float16)0.0f};
            if (rowa < N_ROWS) v = *(const v8h*)(ap + kt * 32);
            af[kt] = v;
        }

        v4f acc[8];
        #pragma unroll
        for (int nt = 0; nt < 8; ++nt) acc[nt] = (v4f){0.0f, 0.0f, 0.0f, 0.0f};

        #pragma unroll
        for (int kt = 0; kt < 4; ++kt) {
            #pragma unroll
            for (int nt = 0; nt < 8; ++nt) {
                acc[nt] = __builtin_amdgcn_mfma_f32_16x16x32_f16(af[kt], bf[kt][nt], acc[nt], 0, 0, 0);
            }
        }

        // relu -> row-sum -> normalize -> LDS D-tile
        #pragma unroll
        for (int reg = 0; reg < 4; ++reg) {
            float vals[8];
            float vsum = 0.0f;
            #pragma unroll
            for (int nt = 0; nt < 8; ++nt) {
                const float v = fmaxf(acc[nt][reg], 0.0f);
                vals[nt] = v;
                vsum += v;
            }
            vsum += __shfl_xor(vsum, 1);
            vsum += __shfl_xor(vsum, 2);
            vsum += __shfl_xor(vsum, 4);
            vsum += __shfl_xor(vsum, 8);
            const float inv = 1.0f / (vsum + EPSF);
            const int drow = wv * 16 + rgrp + reg;
            #pragma unroll
            for (int nt = 0; nt < 8; ++nt) {
                sD[drow][nt * 16 + tcol] = vals[nt] * inv;
            }
        }
        __syncthreads();

        // flipped float4 stores: out[row][124-4cb] = reversed(sD[row][4cb..4cb+3])
        const int grow = tile * ROWS_BLK + srow;
        if (grow < N_ROWS) {
            float* op = out_agg + (size_t)grow * T_LEN;
            #pragma unroll
            for (int c8 = 0; c8 < 8; ++c8) {
                const int cb = scb0 + c8;
                const float4 v = *(const float4*)&sD[srow][4 * cb];
                float4 r;
                r.x = v.w; r.y = v.z; r.z = v.y; r.w = v.x;
                *(float4*)&op[124 - 4 * cb] = r;
            }
        }
        __syncthreads();
    }
}

// ---------------- K3: coords as f32 (unchanged) ----------------
__global__ void IRFAggregator_39049842655549_kernel(const int* __restrict__ edges,
                                                    float* __restrict__ out) {
    const int M = P_PATHS + N_NODES;
    const int i = blockIdx.x * blockDim.x + threadIdx.x;
    if (i >= 2 * M) return;
    int v;
    if (i < P_PATHS) {
        v = edges[i * L_EDGES];
    } else if (i < M) {
        v = i - P_PATHS;
    } else {
        const int j = i - M;
        if (j < P_PATHS) v = edges[j * L_EDGES + L_EDGES - 1];
        else             v = j - P_PATHS;
    }
    out[i] = (float)v;
}

extern "C" void kernel_launch(void* const* d_in, const int* in_sizes, int n_in,
                              void* d_out, int out_size, void* d_ws, size_t ws_size,
                              hipStream_t stream) {
    const float* params = (const float*)d_in[0];
    const int*   edges  = (const int*)d_in[1];

    _Float16* freqh = (_Float16*)d_ws;                                 // 12.8 MB
    _Float16* Wt    = (_Float16*)((char*)d_ws + FREQ_BYTES);           // 32 KB @ 26 MB
    _Float16* W2t   = (_Float16*)((char*)d_ws + FREQ_BYTES + 65536);   // 32 KB
    _Float16* Atile = (_Float16*)((char*)d_ws + ATILE_OFF);            // 51.2 MB @ 32 MB
    _Float16* xtab  = (_Float16*)((char*)d_ws + XTAB_OFF);             // 12.8 MB @ 96 MB
    float4*   pcons = (float4*)((char*)d_ws + PCON_OFF);               // 800 KB @ 112 MB
    float* out      = (float*)d_out;
    float* out_agg  = out + COORD_ELEMS;

    IRFAggregator_39049842655549_kernel<<<(int)((COORD_ELEMS + 255) / 256), 256, 0, stream>>>(edges, out);
    irfa49x_setup<<<128 + (N_NODES + 255) / 256, 256, 0, stream>>>(params, Wt, W2t, pcons);
    irfa49w_xgen<<<N_NODES / 2, 256, 0, stream>>>(pcons, xtab);
    irfa49x_spec<<<STILES, 256, 0, stream>>>(xtab, W2t, freqh);
    irfa49y_prod<<<(P_PATHS * 32) / 256, 256, 0, stream>>>(freqh, edges, Atile);
    irfa49y_gemm<<<GEMM_GRID, 256, 0, stream>>>(Atile, freqh, Wt, out_agg);
}

// Round 26
// 114.854 us; speedup vs baseline: 1.2233x; 1.2233x over previous
//
#include <hip/hip_runtime.h>
#include <hip/hip_bf16.h>

#define N_NODES 50000
#define P_PATHS 200000
#define N_ROWS  250000
#define L_EDGES 6
#define T_LEN   128
#define F_BINS  65
#define EPSF    1e-12f
#define PIF     3.14159265358979323846f
#define COORD_ELEMS ((size_t)2 * (P_PATHS + N_NODES))   // 500000 f32
#define FREQ_BYTES  ((size_t)N_NODES * F_BINS * 8)      // 26 MB mark (Wt)
#define ATILE_OFF   ((size_t)32 * 1024 * 1024)          // A-tile at +32 MB (64 MB)
#define PCON_OFF    ((size_t)112 * 1024 * 1024)         // per-node consts
#define KDIM  128      // packed K: 64 complex pairs (f64 folded into bin0.im)
#define KPADN 128      // fp16 freq-table row stride (halves) = 256 B aligned
#define ROWS_BLK 64
#define TILES ((N_ROWS + ROWS_BLK - 1) / ROWS_BLK)      // 3907
#define GEMM_GRID 1024

typedef _Float16 v2h __attribute__((ext_vector_type(2)));
typedef _Float16 v8h __attribute__((ext_vector_type(8)));
typedef float    v4f __attribute__((ext_vector_type(4)));

__device__ __forceinline__ float softplus_(float x) {
    const float e = __expf(-fabsf(x));
    return fmaxf(x, 0.0f) + __logf(1.0f + e);
}

__device__ __forceinline__ float lgamma_pos_(float x) {
    const float ser = 1.000000000190015f
                    + 76.18009172947146f     / (x + 1.0f)
                    - 86.50532032941677f     / (x + 2.0f)
                    + 24.01409824083091f     / (x + 3.0f)
                    - 1.231739572450155f     / (x + 4.0f)
                    + 0.1208650973866179e-2f / (x + 5.0f)
                    - 0.5395239384953e-5f    / (x + 6.0f);
    const float tmp = x + 5.5f;
    return (x + 0.5f) * __logf(tmp) - tmp + __logf(2.5066282746310005f * ser / x);
}

// ---------------- K0: merged setup — Wt (blocks 0..63) + pcons (blocks 64..) ----------------
__global__ __launch_bounds__(256) void irfa49z_setup(const float* __restrict__ params,
                                                     _Float16* __restrict__ Wt,
                                                     float4* __restrict__ pcons) {
    const int b = blockIdx.x;
    if (b < 64) {
        const int idx = b * 256 + threadIdx.x;           // 128*128
        const int t  = idx >> 7;
        const int kk = idx & 127;
        int j; float cj; bool is_sin;
        if (kk == 1) { j = 64; cj = 1.0f; is_sin = false; }
        else {
            j = kk >> 1;
            cj = (j == 0) ? 1.0f : 2.0f;
            is_sin = (kk & 1);
        }
        const int m = (j * t) & 127;
        const float th = (float)m * (PIF / 64.0f);
        const float tri = is_sin ? -__sinf(th) : __cosf(th);
        Wt[idx] = (_Float16)(cj * tri * (1.0f / 128.0f));
    } else {
        const int n = (b - 64) * 256 + threadIdx.x;
        if (n >= N_NODES) return;
        const float a  = softplus_(params[2 * n + 0]) + 1.0f;
        const float bb = softplus_(params[2 * n + 1]) + 0.5f;
        const float lg = lgamma_pos_(a);
        const float lb = __logf(bb);
        float4 pc;
        pc.x = a - 1.0f;          // am1
        pc.y = 1.0f / bb;         // rb
        pc.z = -lg - a * lb;      // cst
        pc.w = 0.0f;
        pcons[n] = pc;
    }
}

// ---------------- K1: rfft -> packed fp16 table [node][128]; preamble from pcons ----------------
__global__ void irfa49z_freq(const float4* __restrict__ pcons, _Float16* __restrict__ freqh) {
    __shared__ float sx[8][T_LEN];
    __shared__ float su[8][64];
    __shared__ float sv[8][64];
    const int tid  = threadIdx.x;
    const int slot = tid >> 5;
    const int tl   = tid & 31;
    const int n    = blockIdx.x * 8 + slot;
    _Float16* fh   = freqh + (size_t)n * KPADN;

    const float4 pc = pcons[n];           // broadcast, L1-hit
    const float am1 = pc.x, rb = pc.y, cst = pc.z;

    float S = 0.0f;
    #pragma unroll
    for (int j = 0; j < 4; ++j) {
        const float tc = (float)(tl + 32 * j) + 0.5f;
        const float x  = __expf(fmaf(am1, __logf(tc), fmaf(-tc, rb, cst)));
        sx[slot][tl + 32 * j] = x;
        S += x;
    }

    float s0  = S;
    float s64 = (tl & 1) ? -S : S;
    float c32 = ((tl & 3) == 0) ? S : (((tl & 3) == 2) ? -S : 0.0f);
    float s32 = ((tl & 3) == 1) ? S : (((tl & 3) == 3) ? -S : 0.0f);
    #pragma unroll
    for (int m = 16; m; m >>= 1) {
        s0  += __shfl_xor(s0, m);
        s64 += __shfl_xor(s64, m);
        c32 += __shfl_xor(c32, m);
        s32 += __shfl_xor(s32, m);
    }
    __syncthreads();

    {
        const int i1 = tl + 1;
        const float xa = sx[slot][i1], xb = sx[slot][T_LEN - i1];
        su[slot][i1] = xa + xb;
        sv[slot][i1] = xa - xb;
        if (tl < 31) {
            const int i2 = tl + 33;
            const float xc = sx[slot][i2], xd = sx[slot][T_LEN - i2];
            su[slot][i2] = xc + xd;
            sv[slot][i2] = xc - xd;
        }
    }
    __syncthreads();

    if (tl == 0) {
        v2h h;
        h[0] = (_Float16)s0;  h[1] = (_Float16)s64;    *(v2h*)(fh + 0)  = h;  // bin0.re, f64.re
        h[0] = (_Float16)c32; h[1] = (_Float16)(-s32); *(v2h*)(fh + 64) = h;  // bin32
        return;
    }

    const float x0v  = sx[slot][0];
    const float x64v = sx[slot][64];
    const int   k    = tl;
    const float th   = (float)k * (PIF / 64.0f);
    const float c1 = __cosf(th), s1 = __sinf(th);
    const float c2 = 2.0f * c1 * c1 - 1.0f;
    const float s2 = 2.0f * s1 * c1;
    const float K  = 2.0f * c2;

    float ue1 = 0.0f, ue2 = 0.0f, ve1 = 0.0f, ve2 = 0.0f;
    float uo1 = 0.0f, uo2 = 0.0f, vo1 = 0.0f, vo2 = 0.0f;
    #pragma unroll
    for (int m = 31; m >= 1; --m) {
        const float2 uu = *(const float2*)&su[slot][2 * m];
        const float2 vv = *(const float2*)&sv[slot][2 * m];
        float v0;
        v0 = fmaf(K, ue1, uu.x - ue2); ue2 = ue1; ue1 = v0;
        v0 = fmaf(K, ve1, vv.x - ve2); ve2 = ve1; ve1 = v0;
        v0 = fmaf(K, uo1, uu.y - uo2); uo2 = uo1; uo1 = v0;
        v0 = fmaf(K, vo1, vv.y - vo2); vo2 = vo1; vo1 = v0;
    }
    {
        float v0;
        v0 = fmaf(K, uo1, su[slot][1] - uo2); uo2 = uo1; uo1 = v0;
        v0 = fmaf(K, vo1, sv[slot][1] - vo2); vo2 = vo1; vo1 = v0;
    }

    const float Ec = fmaf(ue1, c2, -ue2);
    const float Es = ve1 * s2;
    const float ReSu = fmaf(-uo2, c2, uo1);
    const float ImSu = uo2 * s2;
    const float Oc   = c1 * ReSu - s1 * ImSu;
    const float ReSv = fmaf(-vo2, c2, vo1);
    const float ImSv = vo2 * s2;
    const float Os   = s1 * ReSv + c1 * ImSv;

    const float base = x0v + ((k & 1) ? -x64v : x64v);
    v2h h;
    h[0] = (_Float16)(base + Ec + Oc);
    h[1] = (_Float16)(-(Es + Os));
    *(v2h*)(fh + 2 * k) = h;
    h[0] = (_Float16)(base + Ec - Oc);
    h[1] = (_Float16)(Es - Os);
    *(v2h*)(fh + 2 * (64 - k)) = h;
}

// ---------------- K2a: spectral product -> packed A-tile (r21 form, all 250k rows) ----------------
__global__ __launch_bounds__(256) void irfa49t_prod(const _Float16* __restrict__ freqh,
                                                    const int* __restrict__ edges,
                                                    _Float16* __restrict__ Atile) {
    const int gt  = blockIdx.x * 256 + threadIdx.x;   // grid exact: 250000*32/256
    const int row = gt >> 5;
    const int tl  = gt & 31;
    _Float16* op = Atile + (size_t)row * KDIM;

    if (row < P_PATHS) {
        const int eb = row * L_EDGES;
        v2h av[L_EDGES], bv[L_EDGES];
        #pragma unroll
        for (int j = 0; j < L_EDGES; ++j) {
            const _Float16* fh = freqh + (size_t)edges[eb + j] * KPADN;
            av[j] = *(const v2h*)(fh + 2 * tl);
            bv[j] = *(const v2h*)(fh + 64 + 2 * tl);
        }
        float p1r = 1.0f, p1i = 0.0f, p2r = 1.0f, p2i = 0.0f, q = 1.0f;
        #pragma unroll
        for (int j = 0; j < L_EDGES; ++j) {
            const float ax  = (float)av[j][0];
            const float ayr = (float)av[j][1];
            const float ay  = (tl == 0) ? 0.0f : ayr;    // bin0.im slot holds f64.re
            float t1 = p1r * ax - p1i * ay;
            p1i      = p1r * ay + p1i * ax;
            p1r = t1;
            q *= ayr;
            const float bx = (float)bv[j][0], by = (float)bv[j][1];
            float t2 = p2r * bx - p2i * by;
            p2i      = p2r * by + p2i * bx;
            p2r = t2;
        }
        v2h h;
        h[0] = (_Float16)p1r;
        h[1] = (tl == 0) ? (_Float16)q : (_Float16)p1i;
        *(v2h*)(op + 2 * tl) = h;
        h[0] = (_Float16)p2r; h[1] = (_Float16)p2i;
        *(v2h*)(op + 64 + 2 * tl) = h;
    } else {
        const _Float16* fh = freqh + (size_t)(row - P_PATHS) * KPADN;
        *(v2h*)(op + 2 * tl)      = *(const v2h*)(fh + 2 * tl);
        *(v2h*)(op + 64 + 2 * tl) = *(const v2h*)(fh + 64 + 2 * tl);
    }
}

// ---------------- K2b: persistent MFMA GEMM, B-in-registers, direct stores (r21 form) ----------------
__global__ __launch_bounds__(256, 2) void irfa49u_gemm(const _Float16* __restrict__ Atile,
                                                       const _Float16* __restrict__ Wt,
                                                       float* __restrict__ out_agg) {
    const int tid  = threadIdx.x;
    const int wv   = tid >> 6;
    const int lane = tid & 63;
    const int tcol = lane & 15;
    const int kg   = lane >> 4;
    const int rgrp = kg * 4;

    v8h bf[4][8];
    #pragma unroll
    for (int kt = 0; kt < 4; ++kt) {
        #pragma unroll
        for (int nt = 0; nt < 8; ++nt) {
            bf[kt][nt] = *(const v8h*)&Wt[(nt * 16 + tcol) * KDIM + kt * 32 + kg * 8];
        }
    }

    for (int tile = blockIdx.x; tile < TILES; tile += GEMM_GRID) {
        const int rowa = tile * ROWS_BLK + wv * 16 + tcol;
        const _Float16* ap = Atile + (size_t)rowa * KDIM + kg * 8;

        v8h af[4];
        #pragma unroll
        for (int kt = 0; kt < 4; ++kt) af[kt] = *(const v8h*)(ap + kt * 32);

        v4f acc[8];
        #pragma unroll
        for (int nt = 0; nt < 8; ++nt) acc[nt] = (v4f){0.0f, 0.0f, 0.0f, 0.0f};

        #pragma unroll
        for (int kt = 0; kt < 4; ++kt) {
            #pragma unroll
            for (int nt = 0; nt < 8; ++nt) {
                acc[nt] = __builtin_amdgcn_mfma_f32_16x16x32_f16(af[kt], bf[kt][nt], acc[nt], 0, 0, 0);
            }
        }

        #pragma unroll
        for (int reg = 0; reg < 4; ++reg) {
            float vals[8];
            float vsum = 0.0f;
            #pragma unroll
            for (int nt = 0; nt < 8; ++nt) {
                const float v = fmaxf(acc[nt][reg], 0.0f);
                vals[nt] = v;
                vsum += v;
            }
            vsum += __shfl_xor(vsum, 1);
            vsum += __shfl_xor(vsum, 2);
            vsum += __shfl_xor(vsum, 4);
            vsum += __shfl_xor(vsum, 8);
            const int row = tile * ROWS_BLK + wv * 16 + rgrp + reg;
            if (row < N_ROWS) {
                const float inv = 1.0f / (vsum + EPSF);
                float* op = out_agg + (size_t)row * T_LEN;
                #pragma unroll
                for (int nt = 0; nt < 8; ++nt) {
                    const int t = nt * 16 + tcol;
                    op[127 - t] = vals[nt] * inv;
                }
            }
        }
    }
}

// ---------------- K3: coords as f32 (unchanged) ----------------
__global__ void IRFAggregator_39049842655549_kernel(const int* __restrict__ edges,
                                                    float* __restrict__ out) {
    const int M = P_PATHS + N_NODES;
    const int i = blockIdx.x * blockDim.x + threadIdx.x;
    if (i >= 2 * M) return;
    int v;
    if (i < P_PATHS) {
        v = edges[i * L_EDGES];
    } else if (i < M) {
        v = i - P_PATHS;
    } else {
        const int j = i - M;
        if (j < P_PATHS) v = edges[j * L_EDGES + L_EDGES - 1];
        else             v = j - P_PATHS;
    }
    out[i] = (float)v;
}

extern "C" void kernel_launch(void* const* d_in, const int* in_sizes, int n_in,
                              void* d_out, int out_size, void* d_ws, size_t ws_size,
                              hipStream_t stream) {
    const float* params = (const float*)d_in[0];
    const int*   edges  = (const int*)d_in[1];

    _Float16* freqh = (_Float16*)d_ws;                                 // 12.8 MB
    _Float16* Wt    = (_Float16*)((char*)d_ws + FREQ_BYTES);           // 32 KB @ 26 MB
    _Float16* Atile = (_Float16*)((char*)d_ws + ATILE_OFF);            // 64 MB @ 32 MB
    float4*   pcons = (float4*)((char*)d_ws + PCON_OFF);               // 800 KB @ 112 MB
    float* out      = (float*)d_out;
    float* out_agg  = out + COORD_ELEMS;

    IRFAggregator_39049842655549_kernel<<<(int)((COORD_ELEMS + 255) / 256), 256, 0, stream>>>(edges, out);
    irfa49z_setup<<<64 + (N_NODES + 255) / 256, 256, 0, stream>>>(params, Wt, pcons);
    irfa49z_freq<<<N_NODES / 8, 256, 0, stream>>>(pcons, freqh);
    irfa49t_prod<<<(N_ROWS * 32) / 256, 256, 0, stream>>>(freqh, edges, Atile);
    irfa49u_gemm<<<GEMM_GRID, 256, 0, stream>>>(Atile, Wt, out_agg);
}